// Round 11
// baseline (198.132 us; speedup 1.0000x reference)
//
#include <hip/hip_runtime.h>
#include <hip/hip_bf16.h>

typedef short bf16x8 __attribute__((ext_vector_type(8)));
typedef float f32x4 __attribute__((ext_vector_type(4)));

#define E_TOTAL 2000000
#define MT 64
#define NTILES (E_TOTAL / MT)   // 31250 exactly
#define PGRID 1024              // persistent grid: 4 blocks/CU x 256 CU

#define NU 100000
#define NV 20000
#define NBU ((NU + 63) / 64)    // 1563
#define NBV ((NV + 63) / 64)    // 313

// ws layout (ushort element offsets)
#define OFF_W1UG 0              // 64x64 transposed bf16(W1u)
#define OFF_W1VG 4096           // 64x64 transposed bf16(W1v)
#define OFF_B2G  8192           // 80x64 transposed bf16([W2 | W2@Wp | 0])
#define OFF_U1   16384          // 100000x64 bf16
#define OFF_V1   (16384 + 6400000)
#define WS_NEEDED_BYTES ((size_t)(OFF_V1 + 1280000) * 2)   // 15,392,768 B

// fallback (old path) ws layout: W1g (64x128) @0, B2g @8192
#define FB_XP 136
#define FB_GP 72

__device__ __forceinline__ unsigned short f2bf(float x) {
  __hip_bfloat16 h = __float2bfloat16(x);
  return __builtin_bit_cast(unsigned short, h);
}
__device__ __forceinline__ float bf2f(unsigned short u) {
  unsigned int v = ((unsigned int)u) << 16;
  return __builtin_bit_cast(float, v);
}
__device__ __forceinline__ float gelu_exact(float x) {
  return 0.5f * x * (1.0f + erff(x * 0.70710678118654752f));
}
// Branch-free tanh-GELU (max dev from exact ~2e-4, below bf16 rounding).
__device__ __forceinline__ float gelu_fast(float x) {
  float x2 = x * x;
  float inner = __builtin_fmaf(0.044715f * x, x2, x);
  float e = __builtin_amdgcn_exp2f(inner * 2.3022081f);   // 2*k*log2(e)
  float r = __builtin_amdgcn_rcpf(e + 1.0f);
  return __builtin_fmaf(-x, r, x);
}

// ---------------- prep: weight repack ----------------
__global__ void prep_w(const float* __restrict__ W1, const float* __restrict__ W2,
                       const float* __restrict__ Wp, unsigned short* __restrict__ ws) {
  int t = blockIdx.x * blockDim.x + threadIdx.x;
  int stride = gridDim.x * blockDim.x;
  unsigned short* W1ug = ws + OFF_W1UG;
  unsigned short* W1vg = ws + OFF_W1VG;
  unsigned short* B2g  = ws + OFF_B2G;
  for (int i = t; i < 4096; i += stride) {
    int n = i >> 6, k = i & 63;
    int xc = 32 * (k >> 4) + (k & 15);
    W1ug[i] = f2bf(W1[xc * 64 + n]);
    W1vg[i] = f2bf(W1[(xc + 16) * 64 + n]);
  }
  for (int i = t; i < 80 * 64; i += stride) {
    int n = i >> 6, k = i & 63;
    float v;
    if (n < 64) {
      v = W2[k * 64 + n];
    } else if (n < 69) {
      int c = n - 64;
      float s = 0.f;
      for (int j = 0; j < 64; ++j) s += W2[k * 64 + j] * Wp[j * 5 + c];
      v = s;
    } else {
      v = 0.f;
    }
    B2g[i] = f2bf(v);
  }
}

// ---------------- prep: U1 = ufeat@W1u, V1 = ifeat@W1v (bf16 out, swapped MFMA) ----------------
__global__ __launch_bounds__(256)
void prep_uv(const float* __restrict__ ufeat, const float* __restrict__ ifeat,
             const unsigned short* __restrict__ ws, unsigned short* __restrict__ wsmut) {
  const bool isU = (blockIdx.x < NBU);
  const int rows0 = (isU ? blockIdx.x : blockIdx.x - NBU) * 64;
  const int nrows = isU ? NU : NV;
  const float* feat = isU ? ufeat : ifeat;
  const unsigned short* Wg = ws + (isU ? OFF_W1UG : OFF_W1VG);
  unsigned short* outp = wsmut + (isU ? OFF_U1 : OFF_V1);

  const int lane = threadIdx.x & 63;
  const int w    = threadIdx.x >> 6;
  const int lr   = lane & 15;
  const int q    = lane >> 4;

  int row = rows0 + w * 16 + lr;
  int rowc = row < nrows ? row : nrows - 1;

  const f32x4 fz = {0.f, 0.f, 0.f, 0.f};
  f32x4 acc[4] = {fz, fz, fz, fz};
  #pragma unroll
  for (int kk = 0; kk < 2; ++kk) {
    int k0 = kk * 32 + q * 8;
    float4 fa = *reinterpret_cast<const float4*>(feat + (size_t)rowc * 64 + k0);
    float4 fb = *reinterpret_cast<const float4*>(feat + (size_t)rowc * 64 + k0 + 4);
    bf16x8 a;
    a[0] = (short)f2bf(fa.x); a[1] = (short)f2bf(fa.y);
    a[2] = (short)f2bf(fa.z); a[3] = (short)f2bf(fa.w);
    a[4] = (short)f2bf(fb.x); a[5] = (short)f2bf(fb.y);
    a[6] = (short)f2bf(fb.z); a[7] = (short)f2bf(fb.w);
    #pragma unroll
    for (int nt = 0; nt < 4; ++nt) {
      bf16x8 b = *reinterpret_cast<const bf16x8*>(&Wg[(nt * 16 + lr) * 64 + k0]);
      acc[nt] = __builtin_amdgcn_mfma_f32_16x16x32_bf16(b, a, acc[nt], 0, 0, 0);
    }
  }
  // swapped C layout: acc[nt][r] = out[row][nt*16+4q+r]
  if (row < nrows) {
    #pragma unroll
    for (int nt = 0; nt < 4; ++nt) {
      ushort4 p;
      p.x = f2bf(acc[nt][0]); p.y = f2bf(acc[nt][1]);
      p.z = f2bf(acc[nt][2]); p.w = f2bf(acc[nt][3]);
      *reinterpret_cast<ushort4*>(&outp[(size_t)row * 64 + nt * 16 + 4 * q]) = p;
    }
  }
}

// ---------------- persistent main: rotating 2-stage register pipeline ----------------
struct Idx2 { int i0, i1; };

__device__ __forceinline__ void idx_load(Idx2& ix, int tile, const int* __restrict__ src,
                                         const int* __restrict__ dst, int elane) {
  int e = tile * MT + elane;
  ix.i0 = src[e];
  ix.i1 = dst[e];
}

__device__ __forceinline__ void gather4(bf16x8& u0, bf16x8& u1, bf16x8& v0, bf16x8& v1,
                                        const Idx2& ix,
                                        const unsigned short* __restrict__ U1,
                                        const unsigned short* __restrict__ V1, int q8) {
  const unsigned short* up = U1 + (size_t)ix.i0 * 64 + q8;
  const unsigned short* vp = V1 + (size_t)ix.i1 * 64 + q8;
  u0 = *reinterpret_cast<const bf16x8*>(up);
  u1 = *reinterpret_cast<const bf16x8*>(up + 32);
  v0 = *reinterpret_cast<const bf16x8*>(vp);
  v1 = *reinterpret_cast<const bf16x8*>(vp + 32);
}

// swapped GEMM2: lane (lr,q) reg r = h[edge=tile*64+w*16+lr][col=nt*16+4q+r]
__device__ __forceinline__ void compute_store(
    const bf16x8 b2lo[5], const bf16x8 b2hi[5],
    bf16x8 u0, bf16x8 u1, bf16x8 v0, bf16x8 v1,
    int tile, int w, int lr, int q,
    float* __restrict__ out_h, float* __restrict__ out_score) {
  const f32x4 fz = {0.f, 0.f, 0.f, 0.f};
  f32x4 acc[5] = {fz, fz, fz, fz, fz};
  bf16x8 g0, g1;
  #pragma unroll
  for (int e = 0; e < 8; ++e) {
    float x = bf2f((unsigned short)u0[e]) + bf2f((unsigned short)v0[e]);
    g0[e] = (short)f2bf(gelu_fast(x));
  }
  #pragma unroll
  for (int e = 0; e < 8; ++e) {
    float y = bf2f((unsigned short)u1[e]) + bf2f((unsigned short)v1[e]);
    g1[e] = (short)f2bf(gelu_fast(y));
  }
  #pragma unroll
  for (int nt = 0; nt < 5; ++nt) {
    acc[nt] = __builtin_amdgcn_mfma_f32_16x16x32_bf16(b2lo[nt], g0, acc[nt], 0, 0, 0);
    acc[nt] = __builtin_amdgcn_mfma_f32_16x16x32_bf16(b2hi[nt], g1, acc[nt], 0, 0, 0);
  }
  const size_t edge = (size_t)(tile * MT + w * 16 + lr);
  #pragma unroll
  for (int nt = 0; nt < 4; ++nt)
    __builtin_nontemporal_store(acc[nt],
        reinterpret_cast<f32x4*>(&out_h[edge * 64 + nt * 16 + 4 * q]));
  if (q == 0) {
    *reinterpret_cast<f32x4*>(&out_score[edge * 5]) = acc[4];   // cols 0..3
  } else if (q == 1) {
    out_score[edge * 5 + 4] = acc[4][0];                        // col 68 -> score col 4
  }
}

__global__ __launch_bounds__(256, 4)
void mlp_main6(const unsigned short* __restrict__ ws,
               const int* __restrict__ src, const int* __restrict__ dst,
               float* __restrict__ out) {
  const unsigned short* U1  = ws + OFF_U1;
  const unsigned short* V1  = ws + OFF_V1;
  const unsigned short* B2g = ws + OFF_B2G;

  const int lane = threadIdx.x & 63;
  const int w    = threadIdx.x >> 6;
  const int lr   = lane & 15;
  const int q    = lane >> 4;
  const int q8   = q * 8;
  const int elane = w * 16 + lr;

  float* out_score = out;                 // [E,5]
  float* out_h     = out + 10000000;      // [E,64]

  // B2 fragments: loaded ONCE per persistent block (loop-invariant, 40 VGPRs)
  bf16x8 b2lo[5], b2hi[5];
  #pragma unroll
  for (int nt = 0; nt < 5; ++nt) {
    b2lo[nt] = *reinterpret_cast<const bf16x8*>(&B2g[(nt * 16 + lr) * 64 + q8]);
    b2hi[nt] = *reinterpret_cast<const bf16x8*>(&B2g[(nt * 16 + lr) * 64 + 32 + q8]);
  }

  // pipeline: idx 2 tiles ahead, gathers 1 tile ahead, compute current.
  Idx2 ia, ib;
  bf16x8 ua0, ua1, va0, va1, ub0, ub1, vb0, vb1;

  int t = blockIdx.x;
  int t1 = t + PGRID;     if (t1 > NTILES - 1) t1 = NTILES - 1;
  idx_load(ia, t,  src, dst, elane);
  idx_load(ib, t1, src, dst, elane);
  gather4(ua0, ua1, va0, va1, ia, U1, V1, q8);

  bool useA = true;
  for (; t < NTILES; t += PGRID) {
    int t2 = t + 2 * PGRID;
    if (t2 > NTILES - 1) t2 = NTILES - 1;   // clamped prefetch (valid junk)
    if (useA) {
      idx_load(ia, t2, src, dst, elane);            // 2 loads, no deps
      gather4(ub0, ub1, vb0, vb1, ib, U1, V1, q8);  // idx resolved an iter ago
      compute_store(b2lo, b2hi, ua0, ua1, va0, va1, t, w, lr, q, out_h, out_score);
    } else {
      idx_load(ib, t2, src, dst, elane);
      gather4(ua0, ua1, va0, va1, ia, U1, V1, q8);
      compute_store(b2lo, b2hi, ub0, ub1, vb0, vb1, t, w, lr, q, out_h, out_score);
    }
    useA = !useA;
  }
}

// ================= fallback path (R5 structure) if ws too small =================
__global__ void prep_kernel_fb(const float* __restrict__ W1, const float* __restrict__ W2,
                               const float* __restrict__ Wp,
                               unsigned short* __restrict__ W1g,
                               unsigned short* __restrict__ B2g) {
  int t = blockIdx.x * blockDim.x + threadIdx.x;
  int stride = gridDim.x * blockDim.x;
  for (int i = t; i < 64 * 128; i += stride) {
    int n = i >> 7, k = i & 127;
    W1g[i] = f2bf(W1[k * 64 + n]);
  }
  for (int i = t; i < 80 * 64; i += stride) {
    int n = i >> 6, k = i & 63;
    float v;
    if (n < 64) v = W2[k * 64 + n];
    else if (n < 69) {
      int c = n - 64; float s = 0.f;
      for (int j = 0; j < 64; ++j) s += W2[k * 64 + j] * Wp[j * 5 + c];
      v = s;
    } else v = 0.f;
    B2g[i] = f2bf(v);
  }
}

__global__ __launch_bounds__(256, 8)
void mlp_main_fb(const float* __restrict__ ufeat, const float* __restrict__ ifeat,
                 const int* __restrict__ src, const int* __restrict__ dst,
                 const unsigned short* __restrict__ W1g, const unsigned short* __restrict__ B2g,
                 float* __restrict__ out) {
  __shared__ __align__(16) unsigned short Xb[MT * FB_XP];
  const int lid  = threadIdx.x;
  const int lane = lid & 63;
  const int w    = lid >> 6;
  const int lr   = lane & 15;
  const int q    = lane >> 4;
  const int lk   = q << 3;
  const int tbase = blockIdx.x * MT;
  const int c  = lid & 15;
  const int rb = lid >> 4;
  int eidx[8];
  #pragma unroll
  for (int j = 0; j < 8; ++j) {
    int r = rb + 16 * j;
    eidx[j] = (r < 64) ? src[tbase + r] : dst[tbase + r - 64];
  }
  #pragma unroll
  for (int j = 0; j < 8; ++j) {
    int r = rb + 16 * j;
    int half = r >> 6;
    int e = r & 63;
    const float* base = (half ? ifeat : ufeat) + (size_t)eidx[j] * 64 + c * 4;
    float4 f = *reinterpret_cast<const float4*>(base);
    int col = ((c >> 2) * 32) + half * 16 + ((c & 3) * 4);
    ushort4 p;
    p.x = f2bf(f.x); p.y = f2bf(f.y); p.z = f2bf(f.z); p.w = f2bf(f.w);
    *reinterpret_cast<ushort4*>(&Xb[e * FB_XP + col]) = p;
  }
  __syncthreads();
  const f32x4 fz = {0.f, 0.f, 0.f, 0.f};
  f32x4 acc1[4] = {fz, fz, fz, fz};
  {
    const unsigned short* Xr = &Xb[(w * 16 + lr) * FB_XP];
    #pragma unroll
    for (int kk = 0; kk < 4; ++kk) {
      int ko = kk * 32 + lk;
      bf16x8 a = *reinterpret_cast<const bf16x8*>(Xr + ko);
      #pragma unroll
      for (int nt = 0; nt < 4; ++nt) {
        bf16x8 b = *reinterpret_cast<const bf16x8*>(&W1g[(nt * 16 + lr) * 128 + ko]);
        acc1[nt] = __builtin_amdgcn_mfma_f32_16x16x32_bf16(a, b, acc1[nt], 0, 0, 0);
      }
    }
  }
  __syncthreads();
  unsigned short* g = Xb;
  #pragma unroll
  for (int nt = 0; nt < 4; ++nt) {
    f32x4 v = acc1[nt];
    #pragma unroll
    for (int r = 0; r < 4; ++r)
      g[(w * 16 + 4 * q + r) * FB_GP + nt * 16 + lr] = f2bf(gelu_exact(v[r]));
  }
  __syncthreads();
  f32x4 acc2[5] = {fz, fz, fz, fz, fz};
  #pragma unroll
  for (int kk = 0; kk < 2; ++kk) {
    int ko = kk * 32 + lk;
    bf16x8 a = *reinterpret_cast<const bf16x8*>(&g[(w * 16 + lr) * FB_GP + ko]);
    #pragma unroll
    for (int nt = 0; nt < 5; ++nt) {
      bf16x8 b = *reinterpret_cast<const bf16x8*>(&B2g[(nt * 16 + lr) * 64 + ko]);
      acc2[nt] = __builtin_amdgcn_mfma_f32_16x16x32_bf16(a, b, acc2[nt], 0, 0, 0);
    }
  }
  float* out_score = out;
  float* out_h     = out + 10000000;
  {
    int er0 = tbase + w * 16 + 4 * q;
    #pragma unroll
    for (int nt = 0; nt < 4; ++nt) {
      #pragma unroll
      for (int r = 0; r < 4; ++r)
        out_h[(size_t)(er0 + r) * 64 + nt * 16 + lr] = acc2[nt][r];
    }
    if (lr < 5) {
      #pragma unroll
      for (int r = 0; r < 4; ++r)
        out_score[(size_t)(er0 + r) * 5 + lr] = acc2[4][r];
    }
  }
}

extern "C" void kernel_launch(void* const* d_in, const int* in_sizes, int n_in,
                              void* d_out, int out_size, void* d_ws, size_t ws_size,
                              hipStream_t stream) {
  const float* ufeat = (const float*)d_in[0];
  const float* ifeat = (const float*)d_in[1];
  const float* W1    = (const float*)d_in[2];
  const float* W2    = (const float*)d_in[3];
  const float* Wp    = (const float*)d_in[4];
  const int*   src   = (const int*)d_in[5];
  const int*   dst   = (const int*)d_in[6];

  unsigned short* ws = (unsigned short*)d_ws;

  if (ws_size >= WS_NEEDED_BYTES) {
    prep_w<<<16, 256, 0, stream>>>(W1, W2, Wp, ws);
    prep_uv<<<NBU + NBV, 256, 0, stream>>>(ufeat, ifeat, ws, ws);
    mlp_main6<<<PGRID, 256, 0, stream>>>(ws, src, dst, (float*)d_out);
  } else {
    unsigned short* W1g = ws;
    unsigned short* B2g = ws + 8192;
    prep_kernel_fb<<<16, 256, 0, stream>>>(W1, W2, Wp, W1g, B2g);
    mlp_main_fb<<<NTILES, 256, 0, stream>>>(ufeat, ifeat, src, dst, W1g, B2g, (float*)d_out);
  }
}